// Round 7
// baseline (35.242 us; speedup 1.0000x reference)
//
#include <hip/hip_runtime.h>
#include <math.h>

#define OUTN  4096
#define CONVN 27
#define NPTS  (OUTN * CONVN)     // 110592
#define NQUAD (NPTS / 4)         // 27648 = 108 * 256 point-quads
#define NB    30
#define NOI   256                // OUTC * INC
#define OI_CHUNK 32              // oi per block
#define NCHUNK (NOI / OI_CHUNK)  // 8

typedef float floatx4 __attribute__((ext_vector_type(4)));  // native vector for nontemporal builtin

// Evaluate the 30 hydrogen-wavefunction basis values for one point.
__device__ __forceinline__ void eval_basis(float r, float theta, float phi,
                                           float* __restrict__ bas)
{
    // ---- angular pieces ----
    const float ct = cosf(theta);
    const float st = sqrtf(fmaxf(1.0f - ct * ct, 0.0f));  // matches ref clip
    float s1, c1;
    sincosf(phi, &s1, &c1);
    const float c2 = c1 * c1 - s1 * s1;
    const float s2 = 2.0f * c1 * s1;
    const float c3 = c2 * c1 - s2 * s1;
    const float s3 = s2 * c1 + c2 * s1;

    // Associated Legendre with Condon–Shortley phase (matches ref _plm)
    const float P11 = -st;
    const float P20 = 0.5f * (3.0f * ct * ct - 1.0f);
    const float P21 = -3.0f * ct * st;
    const float P22 = 3.0f * (1.0f - ct * ct);
    const float P30 = 0.5f * ct * (5.0f * ct * ct - 3.0f);
    const float P31 = -1.5f * (5.0f * ct * ct - 1.0f) * st;
    const float P32 = 15.0f * ct * (1.0f - ct * ct);
    const float P33 = -15.0f * st * st * st;

    // Y_lm normalization constants (sqrtf of literals -> constant-folded)
    const float PI   = 3.14159265358979323846f;
    const float K00  = sqrtf(1.0f / (4.0f * PI));
    const float K10  = sqrtf(3.0f / (4.0f * PI));
    const float SK11 = sqrtf(2.0f) * sqrtf(3.0f / (8.0f * PI));
    const float K20  = sqrtf(5.0f / (4.0f * PI));
    const float SK21 = sqrtf(2.0f) * sqrtf(5.0f / (24.0f * PI));
    const float SK22 = sqrtf(2.0f) * sqrtf(5.0f / (96.0f * PI));
    const float K30  = sqrtf(7.0f / (4.0f * PI));
    const float SK31 = sqrtf(2.0f) * sqrtf(7.0f / (48.0f * PI));
    const float SK32 = sqrtf(2.0f) * sqrtf(7.0f / (480.0f * PI));
    const float SK33 = sqrtf(2.0f) * sqrtf(7.0f / (2880.0f * PI));

    const float Y00  = K00;
    const float Y1m1 = SK11 * P11 * s1;
    const float Y10  = K10 * ct;
    const float Y1p1 = SK11 * P11 * c1;
    const float Y2m2 = SK22 * P22 * s2;
    const float Y2m1 = SK21 * P21 * s1;
    const float Y20  = K20 * P20;
    const float Y2p1 = SK21 * P21 * c1;
    const float Y2p2 = SK22 * P22 * c2;
    const float Y3m3 = SK33 * P33 * s3;
    const float Y3m2 = SK32 * P32 * s2;
    const float Y3m1 = SK31 * P31 * s1;
    const float Y30  = K30 * P30;
    const float Y3p1 = SK31 * P31 * c1;
    const float Y3p2 = SK32 * P32 * c2;
    const float Y3p3 = SK33 * P33 * c3;

    // ---- radial parts R_nl(r), Bohr radius 1, rho = 2r/n ----
    const float e1 = expf(-r);                 // n=1
    const float e2 = expf(-0.5f * r);          // n=2
    const float e3 = expf(-r * (1.0f / 3.0f)); // n=3
    const float e4 = expf(-0.25f * r);         // n=4
    const float q2 = r;
    const float q3 = (2.0f / 3.0f) * r;
    const float q4 = 0.5f * r;

    const float R10 = 2.0f * e1;
    const float R20 = sqrtf(1.0f / 8.0f)       * e2 * (2.0f - q2);
    const float R21 = sqrtf(1.0f / 24.0f)      * e2 * q2;
    const float R30 = sqrtf(8.0f / 486.0f)     * e3 * (3.0f - 3.0f * q3 + 0.5f * q3 * q3);
    const float R31 = sqrtf(8.0f / 3888.0f)    * e3 * q3 * (4.0f - q3);
    const float R32 = sqrtf(8.0f / 19440.0f)   * e3 * q3 * q3;
    const float R40 = 0.0625f                  * e4 * (4.0f - 6.0f * q4 + 2.0f * q4 * q4 - q4 * q4 * q4 * (1.0f / 6.0f));
    const float R41 = sqrtf(0.25f / 960.0f)    * e4 * q4 * (10.0f - 5.0f * q4 + 0.5f * q4 * q4);
    const float R42 = sqrtf(0.125f / 5760.0f)  * e4 * q4 * q4 * (6.0f - q4);
    const float R43 = sqrtf(0.125f / 40320.0f) * e4 * q4 * q4 * q4;

    // ---- basis in QNUMS order ----
    bas[0]  = R10 * Y00;
    bas[1]  = R20 * Y00;
    bas[2]  = R21 * Y1m1;
    bas[3]  = R21 * Y10;
    bas[4]  = R21 * Y1p1;
    bas[5]  = R30 * Y00;
    bas[6]  = R31 * Y1m1;
    bas[7]  = R31 * Y10;
    bas[8]  = R31 * Y1p1;
    bas[9]  = R32 * Y2m2;
    bas[10] = R32 * Y2m1;
    bas[11] = R32 * Y20;
    bas[12] = R32 * Y2p1;
    bas[13] = R32 * Y2p2;
    bas[14] = R40 * Y00;
    bas[15] = R41 * Y1m1;
    bas[16] = R41 * Y10;
    bas[17] = R41 * Y1p1;
    bas[18] = R42 * Y2m2;
    bas[19] = R42 * Y2m1;
    bas[20] = R42 * Y20;
    bas[21] = R42 * Y2p1;
    bas[22] = R42 * Y2p2;
    bas[23] = R43 * Y3m3;
    bas[24] = R43 * Y3m2;
    bas[25] = R43 * Y3m1;
    bas[26] = R43 * Y30;
    bas[27] = R43 * Y3p1;
    bas[28] = R43 * Y3p2;
    bas[29] = R43 * Y3p3;
}

// 4 consecutive points per thread -> dwordx4 stores (1 KB per wave-instr, the
// fill kernel's shape at 6.9 TB/s). bas[4][30] = 120 floats register-resident:
// round 4 spilled ONLY because __launch_bounds__(256,3) capped VGPR at ~170;
// here no min-waves cap (up to 256 VGPR, 2 waves/SIMD). Fill proves store BW
// doesn't need occupancy (87% peak at OccupancyPercent=10).
__global__ __launch_bounds__(256)
void dcconv_basis_gemm(const float* __restrict__ pos,     // (NPTS, 3)
                       const float* __restrict__ coeffs,  // (NOI, NB)
                       float* __restrict__ out)           // (NOI, NPTS)
{
    const int quad = blockIdx.x * 256 + threadIdx.x;  // 0..NQUAD-1, grid exact
    const int oi0  = blockIdx.y * OI_CHUNK;

    // 4 points = 12 contiguous floats of pos -> 3 vector loads
    const floatx4* pv = reinterpret_cast<const floatx4*>(pos) + quad * 3;
    const floatx4 pv0 = pv[0];  // r0 t0 f0 r1
    const floatx4 pv1 = pv[1];  // t1 f1 r2 t2
    const floatx4 pv2 = pv[2];  // f2 r3 t3 f3

    float bas[4][NB];
    eval_basis(pv0.x, pv0.y, pv0.z, bas[0]);
    eval_basis(pv0.w, pv1.x, pv1.y, bas[1]);
    eval_basis(pv1.z, pv1.w, pv2.x, bas[2]);
    eval_basis(pv2.y, pv2.z, pv2.w, bas[3]);

    // einsum slice: out[oi][4 pts] = coeffs[oi] . bas
    // coeffs is wave-uniform -> s_loads; store is dwordx4, lane-contiguous.
    floatx4* outq = reinterpret_cast<floatx4*>(out) + quad;
    #pragma unroll 4
    for (int k = 0; k < OI_CHUNK; ++k) {
        const float* cf = coeffs + (size_t)(oi0 + k) * NB;
        float a0 = 0.0f, a1 = 0.0f, a2 = 0.0f, a3 = 0.0f;
        #pragma unroll
        for (int b = 0; b < NB; ++b) {
            const float c = cf[b];
            a0 = fmaf(c, bas[0][b], a0);
            a1 = fmaf(c, bas[1][b], a1);
            a2 = fmaf(c, bas[2][b], a2);
            a3 = fmaf(c, bas[3][b], a3);
        }
        floatx4 v; v.x = a0; v.y = a1; v.z = a2; v.w = a3;
        __builtin_nontemporal_store(v, &outq[(size_t)(oi0 + k) * (NPTS / 4)]);
    }
}

extern "C" void kernel_launch(void* const* d_in, const int* in_sizes, int n_in,
                              void* d_out, int out_size, void* d_ws, size_t ws_size,
                              hipStream_t stream) {
    const float* pos    = (const float*)d_in[0];  // (4096, 27, 3)
    const float* coeffs = (const float*)d_in[1];  // (16, 16, 30)
    float* out = (float*)d_out;                   // (16, 16, 4096, 27)

    dim3 grid(NQUAD / 256, NCHUNK);  // 108 x 8
    dim3 block(256);
    dcconv_basis_gemm<<<grid, block, 0, stream>>>(pos, coeffs, out);
}

// Round 8
// 32.909 us; speedup vs baseline: 1.0709x; 1.0709x over previous
//
#include <hip/hip_runtime.h>
#include <math.h>

#define OUTN  4096
#define CONVN 27
#define NPTS  (OUTN * CONVN)     // 110592
#define NPAIR (NPTS / 2)         // 55296 = 216 * 256 point-pairs
#define NB    30
#define NOI   256                // OUTC * INC
#define OI_CHUNK 32              // oi per block
#define NCHUNK (NOI / OI_CHUNK)  // 8

typedef float floatx2 __attribute__((ext_vector_type(2)));

// Evaluate the 30 hydrogen-wavefunction basis values for one point.
__device__ __forceinline__ void eval_basis(float r, float theta, float phi,
                                           float* __restrict__ bas)
{
    // ---- angular pieces ----
    const float ct = cosf(theta);
    const float st = sqrtf(fmaxf(1.0f - ct * ct, 0.0f));  // matches ref clip
    float s1, c1;
    sincosf(phi, &s1, &c1);
    const float c2 = c1 * c1 - s1 * s1;
    const float s2 = 2.0f * c1 * s1;
    const float c3 = c2 * c1 - s2 * s1;
    const float s3 = s2 * c1 + c2 * s1;

    // Associated Legendre with Condon–Shortley phase (matches ref _plm)
    const float P11 = -st;
    const float P20 = 0.5f * (3.0f * ct * ct - 1.0f);
    const float P21 = -3.0f * ct * st;
    const float P22 = 3.0f * (1.0f - ct * ct);
    const float P30 = 0.5f * ct * (5.0f * ct * ct - 3.0f);
    const float P31 = -1.5f * (5.0f * ct * ct - 1.0f) * st;
    const float P32 = 15.0f * ct * (1.0f - ct * ct);
    const float P33 = -15.0f * st * st * st;

    // Y_lm normalization constants (sqrtf of literals -> constant-folded)
    const float PI   = 3.14159265358979323846f;
    const float K00  = sqrtf(1.0f / (4.0f * PI));
    const float K10  = sqrtf(3.0f / (4.0f * PI));
    const float SK11 = sqrtf(2.0f) * sqrtf(3.0f / (8.0f * PI));
    const float K20  = sqrtf(5.0f / (4.0f * PI));
    const float SK21 = sqrtf(2.0f) * sqrtf(5.0f / (24.0f * PI));
    const float SK22 = sqrtf(2.0f) * sqrtf(5.0f / (96.0f * PI));
    const float K30  = sqrtf(7.0f / (4.0f * PI));
    const float SK31 = sqrtf(2.0f) * sqrtf(7.0f / (48.0f * PI));
    const float SK32 = sqrtf(2.0f) * sqrtf(7.0f / (480.0f * PI));
    const float SK33 = sqrtf(2.0f) * sqrtf(7.0f / (2880.0f * PI));

    const float Y00  = K00;
    const float Y1m1 = SK11 * P11 * s1;
    const float Y10  = K10 * ct;
    const float Y1p1 = SK11 * P11 * c1;
    const float Y2m2 = SK22 * P22 * s2;
    const float Y2m1 = SK21 * P21 * s1;
    const float Y20  = K20 * P20;
    const float Y2p1 = SK21 * P21 * c1;
    const float Y2p2 = SK22 * P22 * c2;
    const float Y3m3 = SK33 * P33 * s3;
    const float Y3m2 = SK32 * P32 * s2;
    const float Y3m1 = SK31 * P31 * s1;
    const float Y30  = K30 * P30;
    const float Y3p1 = SK31 * P31 * c1;
    const float Y3p2 = SK32 * P32 * c2;
    const float Y3p3 = SK33 * P33 * c3;

    // ---- radial parts R_nl(r), Bohr radius 1, rho = 2r/n ----
    const float e1 = expf(-r);                 // n=1
    const float e2 = expf(-0.5f * r);          // n=2
    const float e3 = expf(-r * (1.0f / 3.0f)); // n=3
    const float e4 = expf(-0.25f * r);         // n=4
    const float q2 = r;
    const float q3 = (2.0f / 3.0f) * r;
    const float q4 = 0.5f * r;

    const float R10 = 2.0f * e1;
    const float R20 = sqrtf(1.0f / 8.0f)       * e2 * (2.0f - q2);
    const float R21 = sqrtf(1.0f / 24.0f)      * e2 * q2;
    const float R30 = sqrtf(8.0f / 486.0f)     * e3 * (3.0f - 3.0f * q3 + 0.5f * q3 * q3);
    const float R31 = sqrtf(8.0f / 3888.0f)    * e3 * q3 * (4.0f - q3);
    const float R32 = sqrtf(8.0f / 19440.0f)   * e3 * q3 * q3;
    const float R40 = 0.0625f                  * e4 * (4.0f - 6.0f * q4 + 2.0f * q4 * q4 - q4 * q4 * q4 * (1.0f / 6.0f));
    const float R41 = sqrtf(0.25f / 960.0f)    * e4 * q4 * (10.0f - 5.0f * q4 + 0.5f * q4 * q4);
    const float R42 = sqrtf(0.125f / 5760.0f)  * e4 * q4 * q4 * (6.0f - q4);
    const float R43 = sqrtf(0.125f / 40320.0f) * e4 * q4 * q4 * q4;

    // ---- basis in QNUMS order ----
    bas[0]  = R10 * Y00;
    bas[1]  = R20 * Y00;
    bas[2]  = R21 * Y1m1;
    bas[3]  = R21 * Y10;
    bas[4]  = R21 * Y1p1;
    bas[5]  = R30 * Y00;
    bas[6]  = R31 * Y1m1;
    bas[7]  = R31 * Y10;
    bas[8]  = R31 * Y1p1;
    bas[9]  = R32 * Y2m2;
    bas[10] = R32 * Y2m1;
    bas[11] = R32 * Y20;
    bas[12] = R32 * Y2p1;
    bas[13] = R32 * Y2p2;
    bas[14] = R40 * Y00;
    bas[15] = R41 * Y1m1;
    bas[16] = R41 * Y10;
    bas[17] = R41 * Y1p1;
    bas[18] = R42 * Y2m2;
    bas[19] = R42 * Y2m1;
    bas[20] = R42 * Y20;
    bas[21] = R42 * Y2p1;
    bas[22] = R42 * Y2p2;
    bas[23] = R43 * Y3m3;
    bas[24] = R43 * Y3m2;
    bas[25] = R43 * Y3m1;
    bas[26] = R43 * Y30;
    bas[27] = R43 * Y3p1;
    bas[28] = R43 * Y3p2;
    bas[29] = R43 * Y3p3;
}

// Round-6 kernel with ONE change: plain stores instead of nontemporal.
// A/B: the 6.9 TB/s fill uses plain stores (L2 write-back aggregation);
// nt was never isolated and is the prime suspect for the 3.5 TB/s plateau.
__global__ __launch_bounds__(256)
void dcconv_basis_gemm(const float* __restrict__ pos,     // (NPTS, 3)
                       const float* __restrict__ coeffs,  // (NOI, NB)
                       float* __restrict__ out)           // (NOI, NPTS)
{
    const int pair = blockIdx.x * 256 + threadIdx.x;  // 0..NPAIR-1, grid exact
    const int p0   = pair * 2;
    const int oi0  = blockIdx.y * OI_CHUNK;

    float bas[2][NB];
    #pragma unroll
    for (int q = 0; q < 2; ++q) {
        const float r     = pos[(p0 + q) * 3 + 0];
        const float theta = pos[(p0 + q) * 3 + 1];
        const float phi   = pos[(p0 + q) * 3 + 2];
        eval_basis(r, theta, phi, bas[q]);
    }

    // einsum slice: out[oi][p0..p0+1] = coeffs[oi] . bas[:][:]
    // coeffs is wave-uniform -> s_loads; store is dwordx2, lane-contiguous.
    floatx2* outp = reinterpret_cast<floatx2*>(out) + pair;
    #pragma unroll 4
    for (int k = 0; k < OI_CHUNK; ++k) {
        const float* cf = coeffs + (size_t)(oi0 + k) * NB;
        float a0 = 0.0f, a1 = 0.0f;
        #pragma unroll
        for (int b = 0; b < NB; ++b) {
            const float c = cf[b];
            a0 = fmaf(c, bas[0][b], a0);
            a1 = fmaf(c, bas[1][b], a1);
        }
        floatx2 v; v.x = a0; v.y = a1;
        outp[(size_t)(oi0 + k) * (NPTS / 2)] = v;  // plain store (was nt)
    }
}

extern "C" void kernel_launch(void* const* d_in, const int* in_sizes, int n_in,
                              void* d_out, int out_size, void* d_ws, size_t ws_size,
                              hipStream_t stream) {
    const float* pos    = (const float*)d_in[0];  // (4096, 27, 3)
    const float* coeffs = (const float*)d_in[1];  // (16, 16, 30)
    float* out = (float*)d_out;                   // (16, 16, 4096, 27)

    dim3 grid(NPAIR / 256, NCHUNK);  // 216 x 8
    dim3 block(256);
    dcconv_basis_gemm<<<grid, block, 0, stream>>>(pos, coeffs, out);
}

// Round 9
// 32.007 us; speedup vs baseline: 1.1011x; 1.0282x over previous
//
#include <hip/hip_runtime.h>
#include <math.h>

#define OUTN  4096
#define CONVN 27
#define NPTS  (OUTN * CONVN)     // 110592
#define NPAIR (NPTS / 2)         // 55296 = 216 * 256 point-pairs
#define NB    30
#define NOI   256                // OUTC * INC
#define OI_CHUNK 32              // oi per block
#define NCHUNK (NOI / OI_CHUNK)  // 8

typedef float floatx2 __attribute__((ext_vector_type(2)));

// Evaluate the 30 hydrogen-wavefunction basis values for one point.
__device__ __forceinline__ void eval_basis(float r, float theta, float phi,
                                           float* __restrict__ bas)
{
    // ---- angular pieces ----
    const float ct = cosf(theta);
    const float st = sqrtf(fmaxf(1.0f - ct * ct, 0.0f));  // matches ref clip
    float s1, c1;
    sincosf(phi, &s1, &c1);
    const float c2 = c1 * c1 - s1 * s1;
    const float s2 = 2.0f * c1 * s1;
    const float c3 = c2 * c1 - s2 * s1;
    const float s3 = s2 * c1 + c2 * s1;

    // Associated Legendre with Condon–Shortley phase (matches ref _plm)
    const float P11 = -st;
    const float P20 = 0.5f * (3.0f * ct * ct - 1.0f);
    const float P21 = -3.0f * ct * st;
    const float P22 = 3.0f * (1.0f - ct * ct);
    const float P30 = 0.5f * ct * (5.0f * ct * ct - 3.0f);
    const float P31 = -1.5f * (5.0f * ct * ct - 1.0f) * st;
    const float P32 = 15.0f * ct * (1.0f - ct * ct);
    const float P33 = -15.0f * st * st * st;

    // Y_lm normalization constants (sqrtf of literals -> constant-folded)
    const float PI   = 3.14159265358979323846f;
    const float K00  = sqrtf(1.0f / (4.0f * PI));
    const float K10  = sqrtf(3.0f / (4.0f * PI));
    const float SK11 = sqrtf(2.0f) * sqrtf(3.0f / (8.0f * PI));
    const float K20  = sqrtf(5.0f / (4.0f * PI));
    const float SK21 = sqrtf(2.0f) * sqrtf(5.0f / (24.0f * PI));
    const float SK22 = sqrtf(2.0f) * sqrtf(5.0f / (96.0f * PI));
    const float K30  = sqrtf(7.0f / (4.0f * PI));
    const float SK31 = sqrtf(2.0f) * sqrtf(7.0f / (48.0f * PI));
    const float SK32 = sqrtf(2.0f) * sqrtf(7.0f / (480.0f * PI));
    const float SK33 = sqrtf(2.0f) * sqrtf(7.0f / (2880.0f * PI));

    const float Y00  = K00;
    const float Y1m1 = SK11 * P11 * s1;
    const float Y10  = K10 * ct;
    const float Y1p1 = SK11 * P11 * c1;
    const float Y2m2 = SK22 * P22 * s2;
    const float Y2m1 = SK21 * P21 * s1;
    const float Y20  = K20 * P20;
    const float Y2p1 = SK21 * P21 * c1;
    const float Y2p2 = SK22 * P22 * c2;
    const float Y3m3 = SK33 * P33 * s3;
    const float Y3m2 = SK32 * P32 * s2;
    const float Y3m1 = SK31 * P31 * s1;
    const float Y30  = K30 * P30;
    const float Y3p1 = SK31 * P31 * c1;
    const float Y3p2 = SK32 * P32 * c2;
    const float Y3p3 = SK33 * P33 * c3;

    // ---- radial parts R_nl(r), Bohr radius 1, rho = 2r/n ----
    const float e1 = expf(-r);                 // n=1
    const float e2 = expf(-0.5f * r);          // n=2
    const float e3 = expf(-r * (1.0f / 3.0f)); // n=3
    const float e4 = expf(-0.25f * r);         // n=4
    const float q2 = r;
    const float q3 = (2.0f / 3.0f) * r;
    const float q4 = 0.5f * r;

    const float R10 = 2.0f * e1;
    const float R20 = sqrtf(1.0f / 8.0f)       * e2 * (2.0f - q2);
    const float R21 = sqrtf(1.0f / 24.0f)      * e2 * q2;
    const float R30 = sqrtf(8.0f / 486.0f)     * e3 * (3.0f - 3.0f * q3 + 0.5f * q3 * q3);
    const float R31 = sqrtf(8.0f / 3888.0f)    * e3 * q3 * (4.0f - q3);
    const float R32 = sqrtf(8.0f / 19440.0f)   * e3 * q3 * q3;
    const float R40 = 0.0625f                  * e4 * (4.0f - 6.0f * q4 + 2.0f * q4 * q4 - q4 * q4 * q4 * (1.0f / 6.0f));
    const float R41 = sqrtf(0.25f / 960.0f)    * e4 * q4 * (10.0f - 5.0f * q4 + 0.5f * q4 * q4);
    const float R42 = sqrtf(0.125f / 5760.0f)  * e4 * q4 * q4 * (6.0f - q4);
    const float R43 = sqrtf(0.125f / 40320.0f) * e4 * q4 * q4 * q4;

    // ---- basis in QNUMS order ----
    bas[0]  = R10 * Y00;
    bas[1]  = R20 * Y00;
    bas[2]  = R21 * Y1m1;
    bas[3]  = R21 * Y10;
    bas[4]  = R21 * Y1p1;
    bas[5]  = R30 * Y00;
    bas[6]  = R31 * Y1m1;
    bas[7]  = R31 * Y10;
    bas[8]  = R31 * Y1p1;
    bas[9]  = R32 * Y2m2;
    bas[10] = R32 * Y2m1;
    bas[11] = R32 * Y20;
    bas[12] = R32 * Y2p1;
    bas[13] = R32 * Y2p2;
    bas[14] = R40 * Y00;
    bas[15] = R41 * Y1m1;
    bas[16] = R41 * Y10;
    bas[17] = R41 * Y1p1;
    bas[18] = R42 * Y2m2;
    bas[19] = R42 * Y2m1;
    bas[20] = R42 * Y20;
    bas[21] = R42 * Y2p1;
    bas[22] = R42 * Y2p2;
    bas[23] = R43 * Y3m3;
    bas[24] = R43 * Y3m2;
    bas[25] = R43 * Y3m1;
    bas[26] = R43 * Y30;
    bas[27] = R43 * Y3p1;
    bas[28] = R43 * Y3p2;
    bas[29] = R43 * Y3p3;
}

// Round-6 structure (2 pts/thread, dwordx2 nt stores) with the einsum
// accumulated as packed float2 -> targets v_pk_fma_f32 (VOP3P, 2x fp32 per
// instruction) to halve einsum VALU issue cycles: the 32 us plateau fits
// a zero-overlap VALU(13us) + store-drain(18.6us) sum; shrink the VALU term.
__global__ __launch_bounds__(256)
void dcconv_basis_gemm(const float* __restrict__ pos,     // (NPTS, 3)
                       const float* __restrict__ coeffs,  // (NOI, NB)
                       float* __restrict__ out)           // (NOI, NPTS)
{
    const int pair = blockIdx.x * 256 + threadIdx.x;  // 0..NPAIR-1, grid exact
    const int oi0  = blockIdx.y * OI_CHUNK;

    // 2 points = 6 contiguous floats, 8B-aligned (pair*24) -> 3x dwordx2
    const floatx2* pv = reinterpret_cast<const floatx2*>(pos) + pair * 3;
    const floatx2 pv0 = pv[0];  // r0 t0
    const floatx2 pv1 = pv[1];  // f0 r1
    const floatx2 pv2 = pv[2];  // t1 f1

    float basA[NB], basB[NB];
    eval_basis(pv0.x, pv0.y, pv1.x, basA);
    eval_basis(pv1.y, pv2.x, pv2.y, basB);

    // pack the two points' basis values into float2 register pairs
    floatx2 bas2[NB];
    #pragma unroll
    for (int b = 0; b < NB; ++b) {
        bas2[b].x = basA[b];
        bas2[b].y = basB[b];
    }

    // einsum slice: out[oi][2 pts] = coeffs[oi] . bas2  (packed fp32 FMA)
    floatx2* outp = reinterpret_cast<floatx2*>(out) + pair;
    #pragma unroll 4
    for (int k = 0; k < OI_CHUNK; ++k) {
        const float* cf = coeffs + (size_t)(oi0 + k) * NB;
        floatx2 acc = (floatx2)(0.0f);
        #pragma unroll
        for (int b = 0; b < NB; ++b) {
            const float c = cf[b];          // wave-uniform -> s_load
            floatx2 cv; cv.x = c; cv.y = c;
            acc = __builtin_elementwise_fma(cv, bas2[b], acc);
        }
        __builtin_nontemporal_store(acc, &outp[(size_t)(oi0 + k) * (NPTS / 2)]);
    }
}

extern "C" void kernel_launch(void* const* d_in, const int* in_sizes, int n_in,
                              void* d_out, int out_size, void* d_ws, size_t ws_size,
                              hipStream_t stream) {
    const float* pos    = (const float*)d_in[0];  // (4096, 27, 3)
    const float* coeffs = (const float*)d_in[1];  // (16, 16, 30)
    float* out = (float*)d_out;                   // (16, 16, 4096, 27)

    dim3 grid(NPAIR / 256, NCHUNK);  // 216 x 8
    dim3 block(256);
    dcconv_basis_gemm<<<grid, block, 0, stream>>>(pos, coeffs, out);
}